// Round 7
// baseline (153.683 us; speedup 1.0000x reference)
//
#include <hip/hip_runtime.h>
#include <math.h>

#define B 32
#define P1 778
#define NF 1538
#define P2 3000
#define PARAM_DIM 61
#define LATENT 64

#define NCH_O2H 6             // 6*512 = 3072 >= 3000 (2 obj pts per thread)
#define NCH_H2O 15
#define CH_H2O 200            // 15*200 = 3000
#define RED1_BLKS 16
#define HC_BLKS 128           // h-combine role blocks (in D2)
#define OC_BLKS 256           // o-combine blocks (D3)

// D1 grid: normals(64) + h2o(960) + red1(16)
#define D1_NRM 64
#define D1_H2O (NCH_H2O * 64)
#define D1_TOT (D1_NRM + D1_H2O + RED1_BLKS)
// D2 grid: o2h(384) + h-combine(128)
#define D2_O2H (NCH_O2H * 64)
#define D2_TOT (D2_O2H + HC_BLKS)

// ws layout (float offsets)
#define NRM_OFF 0                           // 2*B*P1 float4 normals
#define NRM_SZ  (2*B*P1*4)
#define OS_OFF  (NRM_OFF + NRM_SZ)          // 2*B*P2 signed o2h dists
#define OS_SZ   (2*B*P2)
#define HP_OFF  (OS_OFF + OS_SZ)            // NCH_H2O*2*B*P1 chunk partial min d2
#define HP_SZ   (NCH_H2O*2*B*P1)
#define R1_OFF  (HP_OFF + HP_SZ)            // RED1_BLKS*3
#define RH_OFF  (R1_OFF + RED1_BLKS*3)      // HC_BLKS   (h-part partials)
#define RP_OFF  (RH_OFF + HC_BLKS)          // OC_BLKS   (o-part partials)

// ---------------- D1: normals ∥ h2o partial mins ∥ small reductions ----------
__global__ __launch_bounds__(256) void kd1(
    const float* __restrict__ recon_x, const float* __restrict__ x,
    const float* __restrict__ mu, const float* __restrict__ logvar,
    const float* __restrict__ recon_xyz, const float* __restrict__ hand_xyz,
    const int* __restrict__ faces, const float* __restrict__ obj,
    float* __restrict__ ws) {
  __shared__ float smem[5446];   // normals role needs 778*4 + 778*3
  const int tid = threadIdx.x;
  const int bid = blockIdx.x;

  if (bid < D1_NRM) {
    // ---- role: vertex normals ----
    const int set = bid >> 5, b = bid & 31;
    const float* verts = (set == 0 ? recon_xyz : hand_xyz) + b * P1 * 3;
    const int* f = faces + b * NF * 3;
    float4* sv = (float4*)smem;
    float* sn = smem + P1 * 4;
    for (int i = tid; i < P1; i += 256)
      sv[i] = make_float4(verts[3*i], verts[3*i+1], verts[3*i+2], 0.f);
    for (int i = tid; i < P1 * 3; i += 256) sn[i] = 0.f;
    __syncthreads();
    for (int k = tid; k < NF; k += 256) {
      int i0 = f[3*k], i1 = f[3*k+1], i2 = f[3*k+2];
      float4 v0 = sv[i0], v1 = sv[i1], v2 = sv[i2];
      float e0x = v1.x - v0.x, e0y = v1.y - v0.y, e0z = v1.z - v0.z;
      float e1x = v2.x - v0.x, e1y = v2.y - v0.y, e1z = v2.z - v0.z;
      float fx = e0y * e1z - e0z * e1y;
      float fy = e0z * e1x - e0x * e1z;
      float fz = e0x * e1y - e0y * e1x;
      atomicAdd(&sn[3*i0+0], fx); atomicAdd(&sn[3*i0+1], fy); atomicAdd(&sn[3*i0+2], fz);
      atomicAdd(&sn[3*i1+0], fx); atomicAdd(&sn[3*i1+1], fy); atomicAdd(&sn[3*i1+2], fz);
      atomicAdd(&sn[3*i2+0], fx); atomicAdd(&sn[3*i2+1], fy); atomicAdd(&sn[3*i2+2], fz);
    }
    __syncthreads();
    float4* nout = (float4*)(ws + NRM_OFF) + (size_t)(set * B + b) * P1;
    for (int p = tid; p < P1; p += 256) {
      float nx = sn[3*p], ny = sn[3*p+1], nz = sn[3*p+2];
      float nn = sqrtf(nx*nx + ny*ny + nz*nz);
      float inv = 1.f / fmaxf(nn, 1e-6f);
      nout[p] = make_float4(nx*inv, ny*inv, nz*inv, 0.f);
    }

  } else if (bid < D1_NRM + D1_H2O) {
    // ---- role: h2o per-hand partial min over one 200-pt obj chunk ----
    const int t = bid - D1_NRM;
    const int chunk = t >> 6, r = t & 63, set = r >> 5, b = r & 31;
    const float* verts = (set == 0 ? recon_xyz : hand_xyz) + b * P1 * 3;
    const float* op = obj + (size_t)(b * P2 + chunk * CH_H2O) * 3;
    float4* s4 = (float4*)smem;
    for (int i = tid; i < CH_H2O; i += 256) {
      float ox = op[3*i], oy = op[3*i+1], oz = op[3*i+2];
      s4[i] = make_float4(ox, oy, oz, ox*ox + oy*oy + oz*oz);
    }
    __syncthreads();
    float* part = ws + HP_OFF + (size_t)((chunk * 2 + set) * B + b) * P1;
    const int p0 = tid, p1 = tid + 256, p2 = tid + 512;
    float ax = verts[3*p0], ay = verts[3*p0+1], az = verts[3*p0+2];
    float bx = verts[3*p1], by = verts[3*p1+1], bz = verts[3*p1+2];
    float cx = verts[3*p2], cy = verts[3*p2+1], cz = verts[3*p2+2];
    float h2a = ax*ax+ay*ay+az*az, h2b = bx*bx+by*by+bz*bz, h2c = cx*cx+cy*cy+cz*cz;
    float nax = -2.f*ax, nay = -2.f*ay, naz = -2.f*az;
    float nbx = -2.f*bx, nby = -2.f*by, nbz = -2.f*bz;
    float ncx = -2.f*cx, ncy = -2.f*cy, ncz = -2.f*cz;
    float m0 = 3.0e38f, m1 = 3.0e38f, m2 = 3.0e38f;
    #pragma unroll 4
    for (int qq = 0; qq < CH_H2O; ++qq) {
      float4 o = s4[qq];
      m0 = fminf(m0, fmaf(o.x, nax, fmaf(o.y, nay, fmaf(o.z, naz, o.w))));
      m1 = fminf(m1, fmaf(o.x, nbx, fmaf(o.y, nby, fmaf(o.z, nbz, o.w))));
      m2 = fminf(m2, fmaf(o.x, ncx, fmaf(o.y, ncy, fmaf(o.z, ncz, o.w))));
    }
    part[p0] = m0 + h2a;
    part[p1] = m1 + h2b;
    part[p2] = m2 + h2c;
    if (tid < P1 - 768) {
      const int p3 = 768 + tid;
      float tx = verts[3*p3], ty = verts[3*p3+1], tz = verts[3*p3+2];
      float h2t = tx*tx+ty*ty+tz*tz;
      float ntx = -2.f*tx, nty = -2.f*ty, ntz = -2.f*tz;
      float m3 = 3.0e38f;
      for (int qq = 0; qq < CH_H2O; ++qq) {
        float4 o = s4[qq];
        m3 = fminf(m3, fmaf(o.x, ntx, fmaf(o.y, nty, fmaf(o.z, ntz, o.w))));
      }
      part[p3] = m3 + h2t;
    }

  } else {
    // ---- role: param/recon/KLD partial sums ----
    const int blk = bid - D1_NRM - D1_H2O;
    const int gtid = blk * 256 + tid, stride = RED1_BLKS * 256;
    float sp = 0.f, sr = 0.f, sk = 0.f;
    for (int i = gtid; i < B * PARAM_DIM; i += stride) { float d = recon_x[i] - x[i]; sp += d * d; }
    for (int i = gtid; i < B * P1 * 3; i += stride)    { float d = recon_xyz[i] - hand_xyz[i]; sr += d * d; }
    for (int i = gtid; i < B * LATENT; i += stride)    { float lv = logvar[i], m = mu[i]; sk += 1.f + lv - m * m - expf(lv); }
    for (int off = 32; off > 0; off >>= 1) {
      sp += __shfl_down(sp, off, 64);
      sr += __shfl_down(sr, off, 64);
      sk += __shfl_down(sk, off, 64);
    }
    const int wv = tid >> 6;
    if ((tid & 63) == 0) { smem[wv*3] = sp; smem[wv*3+1] = sr; smem[wv*3+2] = sk; }
    __syncthreads();
    if (tid == 0) {
      float a = 0.f, bb = 0.f, c = 0.f;
      for (int w = 0; w < 4; ++w) { a += smem[w*3]; bb += smem[w*3+1]; c += smem[w*3+2]; }
      ws[R1_OFF + blk*3+0] = a; ws[R1_OFF + blk*3+1] = bb; ws[R1_OFF + blk*3+2] = c;
    }
  }
}

// ---------------- D2: o2h signed dists (2 obj/thread) ∥ h-combine ------------
__global__ __launch_bounds__(256) void kd2(
    const float* __restrict__ recon_xyz, const float* __restrict__ hand_xyz,
    const float* __restrict__ obj, const float* __restrict__ vw,
    float* __restrict__ ws) {
  __shared__ float4 s4[P1];
  const int tid = threadIdx.x;
  const int bid = blockIdx.x;

  if (bid < D2_O2H) {
    // ---- o2h: one (set,b,chunk of 512 obj pts); each thread owns 2 ----
    const int chunk = bid >> 6, r = bid & 63, set = r >> 5, b = r & 31;
    const float* verts = (set == 0 ? recon_xyz : hand_xyz) + b * P1 * 3;
    for (int i = tid; i < P1; i += 256) {
      float vx = verts[3*i], vy = verts[3*i+1], vz = verts[3*i+2];
      s4[i] = make_float4(vx, vy, vz, vx*vx + vy*vy + vz*vz + 64.f);  // d' > 0
    }
    __syncthreads();
    const int q0 = chunk * 512 + tid;          // always < 3000
    const int q1 = q0 + 256;
    const bool act1 = q1 < P2;
    const float* op = obj + (size_t)b * P2 * 3;
    float p0x = op[3*q0], p0y = op[3*q0+1], p0z = op[3*q0+2];
    float p1x = 0.f, p1y = 0.f, p1z = 0.f;
    if (act1) { p1x = op[3*q1]; p1y = op[3*q1+1]; p1z = op[3*q1+2]; }
    const float a0 = -2.f*p0x, b0 = -2.f*p0y, c0 = -2.f*p0z;
    const float a1 = -2.f*p1x, b1 = -2.f*p1y, c1 = -2.f*p1z;
    unsigned best0 = 0xFFFFFFFFu, best1 = 0xFFFFFFFFu;
    #pragma unroll 4
    for (int p = 0; p < P1; p += 2) {
      float4 h0 = s4[p], h1 = s4[p+1];
      float d00 = fmaf(h0.x, a0, fmaf(h0.y, b0, fmaf(h0.z, c0, h0.w)));
      float d01 = fmaf(h1.x, a0, fmaf(h1.y, b0, fmaf(h1.z, c0, h1.w)));
      float d10 = fmaf(h0.x, a1, fmaf(h0.y, b1, fmaf(h0.z, c1, h0.w)));
      float d11 = fmaf(h1.x, a1, fmaf(h1.y, b1, fmaf(h1.z, c1, h1.w)));
      unsigned k00 = (__float_as_uint(d00) & 0xFFFFFC00u) | (unsigned)p;
      unsigned k01 = (__float_as_uint(d01) & 0xFFFFFC00u) | (unsigned)(p+1);
      unsigned k10 = (__float_as_uint(d10) & 0xFFFFFC00u) | (unsigned)p;
      unsigned k11 = (__float_as_uint(d11) & 0xFFFFFC00u) | (unsigned)(p+1);
      unsigned n0 = k00 < k01 ? k00 : k01;
      unsigned n1 = k10 < k11 ? k10 : k11;
      best0 = n0 < best0 ? n0 : best0;
      best1 = n1 < best1 ? n1 : best1;
    }
    const float4* nrm = (const float4*)(ws + NRM_OFF) + (size_t)(set * B + b) * P1;
    float* os = ws + OS_OFF + (size_t)(set * B + b) * P2;
    {
      int bi = (int)(best0 & 1023u); bi = bi < P1 ? bi : P1 - 1;
      float4 h = s4[bi]; float4 n = nrm[bi];
      float dx = p0x - h.x, dy = p0y - h.y, dz = p0z - h.z;
      float d2 = fmaf(dx, dx, fmaf(dy, dy, dz * dz));
      float dt = n.x * dx + n.y * dy + n.z * dz;
      float sg = (dt > 0.f) ? 1.f : ((dt < 0.f) ? -1.f : 0.f);
      os[q0] = sqrtf(d2) * sg;
    }
    if (act1) {
      int bi = (int)(best1 & 1023u); bi = bi < P1 ? bi : P1 - 1;
      float4 h = s4[bi]; float4 n = nrm[bi];
      float dx = p1x - h.x, dy = p1y - h.y, dz = p1z - h.z;
      float d2 = fmaf(dx, dx, fmaf(dy, dy, dz * dz));
      float dt = n.x * dx + n.y * dy + n.z * dz;
      float sg = (dt > 0.f) ? 1.f : ((dt < 0.f) ? -1.f : 0.f);
      os[q1] = sqrtf(d2) * sg;
    }

  } else {
    // ---- h-combine: fold chunk mins, weight by vw^0.4, block partials ----
    const int blk = bid - D2_O2H;
    const int gtid = blk * 256 + tid, stride = HC_BLKS * 256;
    float sh = 0.f;
    for (int i = gtid; i < B * P1; i += stride) {
      const int p = i % P1;
      float m0 = 3.0e38f, m1 = 3.0e38f;
      #pragma unroll
      for (int c = 0; c < NCH_H2O; ++c) {
        m0 = fminf(m0, ws[HP_OFF + (size_t)(c*2+0) * B * P1 + i]);
        m1 = fminf(m1, ws[HP_OFF + (size_t)(c*2+1) * B * P1 + i]);
      }
      m0 = fmaxf(m0, 0.f); m1 = fmaxf(m1, 0.f);
      sh += fabsf(sqrtf(m0) - sqrtf(m1)) * powf(vw[p], 0.4f);
    }
    for (int off = 32; off > 0; off >>= 1) sh += __shfl_down(sh, off, 64);
    float* sred = (float*)s4;
    if ((tid & 63) == 0) sred[tid >> 6] = sh;
    __syncthreads();
    if (tid == 0) ws[RH_OFF + blk] = sred[0] + sred[1] + sred[2] + sred[3];
  }
}

// ---------------- D3: o-combine (coalesced), block partials ------------------
__global__ __launch_bounds__(256) void kd3(float* __restrict__ ws) {
  __shared__ float sred[4];
  const int gtid = blockIdx.x * 256 + threadIdx.x;
  const int stride = OC_BLKS * 256;
  float so = 0.f;
  for (int i = gtid; i < B * P2; i += stride) {
    float osA = ws[OS_OFF + i];
    float osB = ws[OS_OFF + (size_t)B * P2 + i];
    bool wdist = (osB < 0.01f) && (osB > -0.005f);
    float w = (osA < 0.f) ? 1.5f : (wdist ? 1.f : 0.1f);
    so += fabsf(osA - osB) * w;
  }
  for (int off = 32; off > 0; off >>= 1) so += __shfl_down(so, off, 64);
  if ((threadIdx.x & 63) == 0) sred[threadIdx.x >> 6] = so;
  __syncthreads();
  if (threadIdx.x == 0)
    ws[RP_OFF + blockIdx.x] = sred[0] + sred[1] + sred[2] + sred[3];
}

// ---------------- D4: finalize (single wave) ---------------------------------
__global__ void kfin(const float* __restrict__ ws, float* __restrict__ out) {
  const int lane = threadIdx.x;
  float sp = 0.f, sr = 0.f, sk = 0.f, sh = 0.f, so = 0.f;
  for (int i = lane; i < RED1_BLKS; i += 64) {
    sp += ws[R1_OFF + i*3+0]; sr += ws[R1_OFF + i*3+1]; sk += ws[R1_OFF + i*3+2];
  }
  for (int i = lane; i < HC_BLKS; i += 64) sh += ws[RH_OFF + i];
  for (int i = lane; i < OC_BLKS; i += 64) so += ws[RP_OFF + i];
  for (int off = 32; off > 0; off >>= 1) {
    sp += __shfl_down(sp, off, 64);
    sr += __shfl_down(sr, off, 64);
    sk += __shfl_down(sk, off, 64);
    sh += __shfl_down(sh, off, 64);
    so += __shfl_down(so, off, 64);
  }
  if (lane == 0) {
    float param_loss = sp / (float)B;
    float recon_loss = sr / (float)B;
    float KLD = -0.5f * sk / (float)B;
    float cvae = recon_loss + KLD;
    float loss_h = 35.f * (1.f - 0.005f) * sh / (float)(B * P1);
    float loss_o = 30.f * (1.f - 0.005f) * so / (float)(B * P2);
    float ho = loss_h + loss_o;
    out[0] = cvae + 0.1f * param_loss + 10.f * ho;
    out[1] = param_loss;
    out[2] = ho;
    out[3] = recon_loss;
    out[4] = KLD;
  }
}

extern "C" void kernel_launch(void* const* d_in, const int* in_sizes, int n_in,
                              void* d_out, int out_size, void* d_ws, size_t ws_size,
                              hipStream_t stream) {
  const float* recon_x   = (const float*)d_in[0];
  const float* x         = (const float*)d_in[1];
  const float* mu        = (const float*)d_in[2];
  const float* logvar    = (const float*)d_in[3];
  const float* recon_xyz = (const float*)d_in[4];
  const float* hand_xyz  = (const float*)d_in[5];
  const int*   faces     = (const int*)d_in[6];
  const float* obj       = (const float*)d_in[7];
  const float* vw        = (const float*)d_in[8];
  float* ws = (float*)d_ws;
  float* out = (float*)d_out;

  kd1<<<dim3(D1_TOT), 256, 0, stream>>>(recon_x, x, mu, logvar,
                                        recon_xyz, hand_xyz, faces, obj, ws);
  kd2<<<dim3(D2_TOT), 256, 0, stream>>>(recon_xyz, hand_xyz, obj, vw, ws);
  kd3<<<dim3(OC_BLKS), 256, 0, stream>>>(ws);
  kfin<<<1, 64, 0, stream>>>(ws, out);
}

// Round 8
// 128.996 us; speedup vs baseline: 1.1914x; 1.1914x over previous
//
#include <hip/hip_runtime.h>
#include <math.h>

#define B 32
#define P1 778
#define NF 1538
#define P2 3000
#define PARAM_DIM 61
#define LATENT 64

// o2h: 4 chunks x 768 obj pts (3 per thread) = 3072 >= 3000
#define NCH_O2H 4
#define CH_O2H 768
// h2o: 15 chunks x 200 obj pts
#define NCH_H2O 15
#define CH_H2O 200
#define RED1_BLKS 16
#define HC_BLKS 128
#define OC_BLKS 192
#define HALF_F 769            // faces per normal-split (2*769 = 1538)

// D1 grid: normals(128) + red1(16)
#define D1_NRM 128
#define D1_TOT (D1_NRM + RED1_BLKS)
// D2 grid: o2h(256) first (longest), then h2o(960)
#define D2_O2H (NCH_O2H * 64)
#define D2_H2O (NCH_H2O * 64)
#define D2_TOT (D2_O2H + D2_H2O)
// D3 grid: o-combine(192) + h-combine(128)
#define D3_TOT (OC_BLKS + HC_BLKS)

// ws layout (float offsets)
#define NP_OFF  0                            // [half][set][b][p] float4 raw normal partials
#define NP_SZ   (2*2*B*P1*4)
#define OS_OFF  (NP_OFF + NP_SZ)             // 2*B*P2 signed o2h dists
#define OS_SZ   (2*B*P2)
#define HP_OFF  (OS_OFF + OS_SZ)             // NCH_H2O*2*B*P1 chunk partial min d2
#define HP_SZ   (NCH_H2O*2*B*P1)
#define R1_OFF  (HP_OFF + HP_SZ)             // RED1_BLKS*3
#define RH_OFF  (R1_OFF + RED1_BLKS*3)       // HC_BLKS
#define RO_OFF  (RH_OFF + HC_BLKS)           // OC_BLKS

// ---------------- D1: raw vertex-normal partials (2 blocks/mesh) + red1 ------
__global__ __launch_bounds__(256) void kd1(
    const float* __restrict__ recon_x, const float* __restrict__ x,
    const float* __restrict__ mu, const float* __restrict__ logvar,
    const float* __restrict__ recon_xyz, const float* __restrict__ hand_xyz,
    const int* __restrict__ faces, float* __restrict__ ws) {
  __shared__ float4 sv[P1];           // 12448 B
  __shared__ float sn[4][2336];       // wave-private accumulators, 37376 B
  const int tid = threadIdx.x;
  const int bid = blockIdx.x;

  if (bid < D1_NRM) {
    const int half = bid >> 6, r = bid & 63, set = r >> 5, b = r & 31;
    const float* verts = (set == 0 ? recon_xyz : hand_xyz) + b * P1 * 3;
    const int* f = faces + b * NF * 3 + half * HALF_F * 3;
    const int nf = (half == 0) ? HALF_F : (NF - HALF_F);
    for (int i = tid; i < P1; i += 256)
      sv[i] = make_float4(verts[3*i], verts[3*i+1], verts[3*i+2], 0.f);
    for (int i = tid; i < 4 * 2336; i += 256) ((float*)sn)[i] = 0.f;
    __syncthreads();
    float* s = sn[tid >> 6];          // wave-private: no cross-wave contention
    for (int k = tid; k < nf; k += 256) {
      int i0 = f[3*k], i1 = f[3*k+1], i2 = f[3*k+2];
      float4 v0 = sv[i0], v1 = sv[i1], v2 = sv[i2];
      float e0x = v1.x - v0.x, e0y = v1.y - v0.y, e0z = v1.z - v0.z;
      float e1x = v2.x - v0.x, e1y = v2.y - v0.y, e1z = v2.z - v0.z;
      float fx = e0y * e1z - e0z * e1y;
      float fy = e0z * e1x - e0x * e1z;
      float fz = e0x * e1y - e0y * e1x;
      atomicAdd(&s[3*i0+0], fx); atomicAdd(&s[3*i0+1], fy); atomicAdd(&s[3*i0+2], fz);
      atomicAdd(&s[3*i1+0], fx); atomicAdd(&s[3*i1+1], fy); atomicAdd(&s[3*i1+2], fz);
      atomicAdd(&s[3*i2+0], fx); atomicAdd(&s[3*i2+1], fy); atomicAdd(&s[3*i2+2], fz);
    }
    __syncthreads();
    // sign(n.v) is invariant under positive scaling -> store RAW sums, no normalize
    float4* np = (float4*)(ws + NP_OFF) + (size_t)((half * 2 + set) * B + b) * P1;
    for (int p = tid; p < P1; p += 256) {
      float nx = sn[0][3*p] + sn[1][3*p] + sn[2][3*p] + sn[3][3*p];
      float ny = sn[0][3*p+1] + sn[1][3*p+1] + sn[2][3*p+1] + sn[3][3*p+1];
      float nz = sn[0][3*p+2] + sn[1][3*p+2] + sn[2][3*p+2] + sn[3][3*p+2];
      np[p] = make_float4(nx, ny, nz, 0.f);
    }
  } else {
    const int blk = bid - D1_NRM;
    const int gtid = blk * 256 + tid, stride = RED1_BLKS * 256;
    float sp = 0.f, sr = 0.f, sk = 0.f;
    for (int i = gtid; i < B * PARAM_DIM; i += stride) { float d = recon_x[i] - x[i]; sp += d * d; }
    for (int i = gtid; i < B * P1 * 3; i += stride)    { float d = recon_xyz[i] - hand_xyz[i]; sr += d * d; }
    for (int i = gtid; i < B * LATENT; i += stride)    { float lv = logvar[i], m = mu[i]; sk += 1.f + lv - m * m - expf(lv); }
    for (int off = 32; off > 0; off >>= 1) {
      sp += __shfl_down(sp, off, 64);
      sr += __shfl_down(sr, off, 64);
      sk += __shfl_down(sk, off, 64);
    }
    float* sred = (float*)sn;
    const int wv = tid >> 6;
    if ((tid & 63) == 0) { sred[wv*3] = sp; sred[wv*3+1] = sr; sred[wv*3+2] = sk; }
    __syncthreads();
    if (tid == 0) {
      float a = 0.f, bb = 0.f, c = 0.f;
      for (int w = 0; w < 4; ++w) { a += sred[w*3]; bb += sred[w*3+1]; c += sred[w*3+2]; }
      ws[R1_OFF + blk*3+0] = a; ws[R1_OFF + blk*3+1] = bb; ws[R1_OFF + blk*3+2] = c;
    }
  }
}

// ---------------- D2: o2h (3 obj/thread) + h2o partial mins ------------------
__global__ __launch_bounds__(256) void kd2(
    const float* __restrict__ recon_xyz, const float* __restrict__ hand_xyz,
    const float* __restrict__ obj, float* __restrict__ ws) {
  __shared__ float4 s4[P1];           // 12448 B (h2o uses first 200)
  const int tid = threadIdx.x;
  const int bid = blockIdx.x;

  if (bid < D2_O2H) {
    // ---- o2h: (set,b,chunk of 768 obj pts); 3 obj pts per thread ----
    const int chunk = bid >> 6, r = bid & 63, set = r >> 5, b = r & 31;
    const float* verts = (set == 0 ? recon_xyz : hand_xyz) + b * P1 * 3;
    for (int i = tid; i < P1; i += 256) {
      float vx = verts[3*i], vy = verts[3*i+1], vz = verts[3*i+2];
      s4[i] = make_float4(vx, vy, vz, vx*vx + vy*vy + vz*vz + 64.f);  // d' > 0
    }
    __syncthreads();
    const int q0 = chunk * CH_O2H + tid;
    const int q1 = q0 + 256;
    const int q2 = q0 + 512;
    const bool act2 = q2 < P2;          // q0,q1 always < 3000
    const float* op = obj + (size_t)b * P2 * 3;
    float p0x = op[3*q0], p0y = op[3*q0+1], p0z = op[3*q0+2];
    float p1x = op[3*q1], p1y = op[3*q1+1], p1z = op[3*q1+2];
    float p2x = 0.f, p2y = 0.f, p2z = 0.f;
    if (act2) { p2x = op[3*q2]; p2y = op[3*q2+1]; p2z = op[3*q2+2]; }
    const float a0 = -2.f*p0x, b0 = -2.f*p0y, c0 = -2.f*p0z;
    const float a1 = -2.f*p1x, b1 = -2.f*p1y, c1 = -2.f*p1z;
    const float a2 = -2.f*p2x, b2 = -2.f*p2y, c2 = -2.f*p2z;
    unsigned best0 = 0xFFFFFFFFu, best1 = 0xFFFFFFFFu, best2 = 0xFFFFFFFFu;
    #pragma unroll 4
    for (int p = 0; p < P1; p += 2) {
      float4 h0 = s4[p], h1 = s4[p+1];
      float d00 = fmaf(h0.x, a0, fmaf(h0.y, b0, fmaf(h0.z, c0, h0.w)));
      float d01 = fmaf(h1.x, a0, fmaf(h1.y, b0, fmaf(h1.z, c0, h1.w)));
      float d10 = fmaf(h0.x, a1, fmaf(h0.y, b1, fmaf(h0.z, c1, h0.w)));
      float d11 = fmaf(h1.x, a1, fmaf(h1.y, b1, fmaf(h1.z, c1, h1.w)));
      float d20 = fmaf(h0.x, a2, fmaf(h0.y, b2, fmaf(h0.z, c2, h0.w)));
      float d21 = fmaf(h1.x, a2, fmaf(h1.y, b2, fmaf(h1.z, c2, h1.w)));
      unsigned k00 = (__float_as_uint(d00) & 0xFFFFFC00u) | (unsigned)p;
      unsigned k01 = (__float_as_uint(d01) & 0xFFFFFC00u) | (unsigned)(p+1);
      unsigned k10 = (__float_as_uint(d10) & 0xFFFFFC00u) | (unsigned)p;
      unsigned k11 = (__float_as_uint(d11) & 0xFFFFFC00u) | (unsigned)(p+1);
      unsigned k20 = (__float_as_uint(d20) & 0xFFFFFC00u) | (unsigned)p;
      unsigned k21 = (__float_as_uint(d21) & 0xFFFFFC00u) | (unsigned)(p+1);
      unsigned n0 = k00 < k01 ? k00 : k01;
      unsigned n1 = k10 < k11 ? k10 : k11;
      unsigned n2 = k20 < k21 ? k20 : k21;
      best0 = n0 < best0 ? n0 : best0;
      best1 = n1 < best1 ? n1 : best1;
      best2 = n2 < best2 ? n2 : best2;
    }
    const float4* np0 = (const float4*)(ws + NP_OFF) + (size_t)(set * B + b) * P1;
    const float4* np1 = np0 + (size_t)2 * B * P1;   // half-1 partials
    float* os = ws + OS_OFF + (size_t)(set * B + b) * P2;
    {
      int bi = (int)(best0 & 1023u); bi = bi < P1 ? bi : P1 - 1;
      float4 h = s4[bi]; float4 na = np0[bi], nb = np1[bi];
      float nx = na.x + nb.x, ny = na.y + nb.y, nz = na.z + nb.z;
      float dx = p0x - h.x, dy = p0y - h.y, dz = p0z - h.z;
      float d2 = fmaf(dx, dx, fmaf(dy, dy, dz * dz));
      float dt = nx * dx + ny * dy + nz * dz;
      float sg = (dt > 0.f) ? 1.f : ((dt < 0.f) ? -1.f : 0.f);
      os[q0] = sqrtf(d2) * sg;
    }
    {
      int bi = (int)(best1 & 1023u); bi = bi < P1 ? bi : P1 - 1;
      float4 h = s4[bi]; float4 na = np0[bi], nb = np1[bi];
      float nx = na.x + nb.x, ny = na.y + nb.y, nz = na.z + nb.z;
      float dx = p1x - h.x, dy = p1y - h.y, dz = p1z - h.z;
      float d2 = fmaf(dx, dx, fmaf(dy, dy, dz * dz));
      float dt = nx * dx + ny * dy + nz * dz;
      float sg = (dt > 0.f) ? 1.f : ((dt < 0.f) ? -1.f : 0.f);
      os[q1] = sqrtf(d2) * sg;
    }
    if (act2) {
      int bi = (int)(best2 & 1023u); bi = bi < P1 ? bi : P1 - 1;
      float4 h = s4[bi]; float4 na = np0[bi], nb = np1[bi];
      float nx = na.x + nb.x, ny = na.y + nb.y, nz = na.z + nb.z;
      float dx = p2x - h.x, dy = p2y - h.y, dz = p2z - h.z;
      float d2 = fmaf(dx, dx, fmaf(dy, dy, dz * dz));
      float dt = nx * dx + ny * dy + nz * dz;
      float sg = (dt > 0.f) ? 1.f : ((dt < 0.f) ? -1.f : 0.f);
      os[q2] = sqrtf(d2) * sg;
    }

  } else {
    // ---- h2o: per-hand partial min over one 200-pt obj chunk ----
    const int t = bid - D2_O2H;
    const int chunk = t >> 6, r = t & 63, set = r >> 5, b = r & 31;
    const float* verts = (set == 0 ? recon_xyz : hand_xyz) + b * P1 * 3;
    const float* op = obj + (size_t)(b * P2 + chunk * CH_H2O) * 3;
    for (int i = tid; i < CH_H2O; i += 256) {
      float ox = op[3*i], oy = op[3*i+1], oz = op[3*i+2];
      s4[i] = make_float4(ox, oy, oz, ox*ox + oy*oy + oz*oz);
    }
    __syncthreads();
    float* part = ws + HP_OFF + (size_t)((chunk * 2 + set) * B + b) * P1;
    const int p0 = tid, p1 = tid + 256, p2 = tid + 512;
    float ax = verts[3*p0], ay = verts[3*p0+1], az = verts[3*p0+2];
    float bx = verts[3*p1], by = verts[3*p1+1], bz = verts[3*p1+2];
    float cx = verts[3*p2], cy = verts[3*p2+1], cz = verts[3*p2+2];
    float h2a = ax*ax+ay*ay+az*az, h2b = bx*bx+by*by+bz*bz, h2c = cx*cx+cy*cy+cz*cz;
    float nax = -2.f*ax, nay = -2.f*ay, naz = -2.f*az;
    float nbx = -2.f*bx, nby = -2.f*by, nbz = -2.f*bz;
    float ncx = -2.f*cx, ncy = -2.f*cy, ncz = -2.f*cz;
    float m0 = 3.0e38f, m1 = 3.0e38f, m2 = 3.0e38f;
    #pragma unroll 4
    for (int qq = 0; qq < CH_H2O; ++qq) {
      float4 o = s4[qq];
      m0 = fminf(m0, fmaf(o.x, nax, fmaf(o.y, nay, fmaf(o.z, naz, o.w))));
      m1 = fminf(m1, fmaf(o.x, nbx, fmaf(o.y, nby, fmaf(o.z, nbz, o.w))));
      m2 = fminf(m2, fmaf(o.x, ncx, fmaf(o.y, ncy, fmaf(o.z, ncz, o.w))));
    }
    part[p0] = m0 + h2a;
    part[p1] = m1 + h2b;
    part[p2] = m2 + h2c;
    if (tid < P1 - 768) {
      const int p3 = 768 + tid;
      float tx = verts[3*p3], ty = verts[3*p3+1], tz = verts[3*p3+2];
      float h2t = tx*tx+ty*ty+tz*tz;
      float ntx = -2.f*tx, nty = -2.f*ty, ntz = -2.f*tz;
      float m3 = 3.0e38f;
      for (int qq = 0; qq < CH_H2O; ++qq) {
        float4 o = s4[qq];
        m3 = fminf(m3, fmaf(o.x, ntx, fmaf(o.y, nty, fmaf(o.z, ntz, o.w))));
      }
      part[p3] = m3 + h2t;
    }
  }
}

// ---------------- D3: o-combine ∥ h-combine ----------------------------------
__global__ __launch_bounds__(256) void kd3(const float* __restrict__ vw,
                                           float* __restrict__ ws) {
  __shared__ float sred[4];
  const int tid = threadIdx.x;
  const int bid = blockIdx.x;
  if (bid < OC_BLKS) {
    const int gtid = bid * 256 + tid, stride = OC_BLKS * 256;
    float so = 0.f;
    for (int i = gtid; i < B * P2; i += stride) {
      float osA = ws[OS_OFF + i];
      float osB = ws[OS_OFF + (size_t)B * P2 + i];
      bool wdist = (osB < 0.01f) && (osB > -0.005f);
      float w = (osA < 0.f) ? 1.5f : (wdist ? 1.f : 0.1f);
      so += fabsf(osA - osB) * w;
    }
    for (int off = 32; off > 0; off >>= 1) so += __shfl_down(so, off, 64);
    if ((tid & 63) == 0) sred[tid >> 6] = so;
    __syncthreads();
    if (tid == 0) ws[RO_OFF + bid] = sred[0] + sred[1] + sred[2] + sred[3];
  } else {
    const int blk = bid - OC_BLKS;
    const int gtid = blk * 256 + tid, stride = HC_BLKS * 256;
    float sh = 0.f;
    for (int i = gtid; i < B * P1; i += stride) {
      const int p = i % P1;
      float m0 = 3.0e38f, m1 = 3.0e38f;
      #pragma unroll
      for (int c = 0; c < NCH_H2O; ++c) {
        m0 = fminf(m0, ws[HP_OFF + (size_t)(c*2+0) * B * P1 + i]);
        m1 = fminf(m1, ws[HP_OFF + (size_t)(c*2+1) * B * P1 + i]);
      }
      m0 = fmaxf(m0, 0.f); m1 = fmaxf(m1, 0.f);
      sh += fabsf(sqrtf(m0) - sqrtf(m1)) * powf(vw[p], 0.4f);
    }
    for (int off = 32; off > 0; off >>= 1) sh += __shfl_down(sh, off, 64);
    if ((tid & 63) == 0) sred[tid >> 6] = sh;
    __syncthreads();
    if (tid == 0) ws[RH_OFF + blk] = sred[0] + sred[1] + sred[2] + sred[3];
  }
}

// ---------------- D4: finalize (single wave) ---------------------------------
__global__ void kfin(const float* __restrict__ ws, float* __restrict__ out) {
  const int lane = threadIdx.x;
  float sp = 0.f, sr = 0.f, sk = 0.f, sh = 0.f, so = 0.f;
  for (int i = lane; i < RED1_BLKS; i += 64) {
    sp += ws[R1_OFF + i*3+0]; sr += ws[R1_OFF + i*3+1]; sk += ws[R1_OFF + i*3+2];
  }
  for (int i = lane; i < HC_BLKS; i += 64) sh += ws[RH_OFF + i];
  for (int i = lane; i < OC_BLKS; i += 64) so += ws[RO_OFF + i];
  for (int off = 32; off > 0; off >>= 1) {
    sp += __shfl_down(sp, off, 64);
    sr += __shfl_down(sr, off, 64);
    sk += __shfl_down(sk, off, 64);
    sh += __shfl_down(sh, off, 64);
    so += __shfl_down(so, off, 64);
  }
  if (lane == 0) {
    float param_loss = sp / (float)B;
    float recon_loss = sr / (float)B;
    float KLD = -0.5f * sk / (float)B;
    float cvae = recon_loss + KLD;
    float loss_h = 35.f * (1.f - 0.005f) * sh / (float)(B * P1);
    float loss_o = 30.f * (1.f - 0.005f) * so / (float)(B * P2);
    float ho = loss_h + loss_o;
    out[0] = cvae + 0.1f * param_loss + 10.f * ho;
    out[1] = param_loss;
    out[2] = ho;
    out[3] = recon_loss;
    out[4] = KLD;
  }
}

extern "C" void kernel_launch(void* const* d_in, const int* in_sizes, int n_in,
                              void* d_out, int out_size, void* d_ws, size_t ws_size,
                              hipStream_t stream) {
  const float* recon_x   = (const float*)d_in[0];
  const float* x         = (const float*)d_in[1];
  const float* mu        = (const float*)d_in[2];
  const float* logvar    = (const float*)d_in[3];
  const float* recon_xyz = (const float*)d_in[4];
  const float* hand_xyz  = (const float*)d_in[5];
  const int*   faces     = (const int*)d_in[6];
  const float* obj       = (const float*)d_in[7];
  const float* vw        = (const float*)d_in[8];
  float* ws = (float*)d_ws;
  float* out = (float*)d_out;

  kd1<<<dim3(D1_TOT), 256, 0, stream>>>(recon_x, x, mu, logvar,
                                        recon_xyz, hand_xyz, faces, ws);
  kd2<<<dim3(D2_TOT), 256, 0, stream>>>(recon_xyz, hand_xyz, obj, ws);
  kd3<<<dim3(D3_TOT), 256, 0, stream>>>(vw, ws);
  kfin<<<1, 64, 0, stream>>>(ws, out);
}